// Round 10
// baseline (800.493 us; speedup 1.0000x reference)
//
#include <hip/hip_runtime.h>
#include <math.h>

#define BS_TOT 32768
#define NN 30
#define HHD 8
#define GHH 16
#define LHH 64
#define SSS 512
#define BBB 64
#define RECON_SIZE (BBB*SSS*NN)   // 983040

__device__ __forceinline__ float fsigmoid(float x) {
    return 1.f / (1.f + __expf(-x));
}
__device__ __forceinline__ float ftanh(float x) {
    float ax = fabsf(x);
    float e = __expf(-2.f * ax);
    float r = (1.f - e) / (1.f + e);
    return copysignf(r, x);
}

// ---------------- K1: GAT + projection (fused) ----------------
#define NB 16
__global__ __launch_bounds__(256) void gat_proj_kernel(
    const float* __restrict__ x, const float* __restrict__ adj,
    const float* __restrict__ W_gat, const float* __restrict__ a_src,
    const float* __restrict__ a_dst, const float* __restrict__ W_proj,
    const float* __restrict__ b_proj, float* __restrict__ gat_seq,
    float* __restrict__ attn_out)
{
    __shared__ __align__(16) float gat[NB][480];
    __shared__ __align__(16) float wchunk[96*64];
    __shared__ float x_s[NB][32];
    __shared__ unsigned adjbits[32];

    const int t = threadIdx.x;
    const int bs_base = blockIdx.x * NB;

    for (int rep = 0; rep < 2; ++rep) {
        int idx = rep*256 + t;
        int bl = idx >> 5, j = idx & 31;
        if (j < NN) x_s[bl][j] = x[(bs_base + bl)*NN + j];
    }
    if (t < NN) {
        unsigned bits = 0;
        for (int j = 0; j < NN; ++j)
            if (adj[t*NN + j] != 0.0f) bits |= (1u << j);
        adjbits[t] = bits;
    }
    __syncthreads();

    const int wave = t >> 6, lane = t & 63;
    const int h = lane >> 5, i = lane & 31;
    const bool act = (i < NN);

    float wg[HHD];
    float s_h = 0.f, t_h = 0.f;
    #pragma unroll
    for (int d = 0; d < HHD; ++d) {
        float w = W_gat[h*HHD + d];
        wg[d] = w;
        s_h += w * a_src[h*HHD + d];
        t_h += w * a_dst[h*HHD + d];
    }

    for (int r = 0; r < 4; ++r) {
        const int bl = wave*4 + r;
        const int bs = bs_base + bl;
        const unsigned bits = act ? adjbits[i & 31] : 0u;
        const float xi = act ? x_s[bl][i] : 0.f;
        const float esrc = xi * s_h;

        float m = -1e30f;
        for (int j = 0; j < NN; ++j) {
            if (bits & (1u << j)) {
                float e = esrc + x_s[bl][j] * t_h;
                e = (e >= 0.f) ? e : 0.2f * e;
                m = fmaxf(m, e);
            }
        }
        float Z = 0.f, Sx = 0.f;
        for (int j = 0; j < NN; ++j) {
            if (bits & (1u << j)) {
                float e = esrc + x_s[bl][j] * t_h;
                e = (e >= 0.f) ? e : 0.2f * e;
                float p = expf(e - m);
                Z += p;
                Sx += p * x_s[bl][j];
            }
        }
        const float wsum = Sx / Z;

        if (act) {
            float tmp[8];
            #pragma unroll
            for (int d = 0; d < 8; ++d) {
                float v = wsum * wg[d];
                tmp[d] = (v > 0.f) ? v : expm1f(v);
            }
            float4 v0 = make_float4(tmp[0], tmp[1], tmp[2], tmp[3]);
            float4 v1 = make_float4(tmp[4], tmp[5], tmp[6], tmp[7]);
            *(float4*)&gat[bl][i*GHH + h*HHD]     = v0;
            *(float4*)&gat[bl][i*GHH + h*HHD + 4] = v1;
        }

        if ((bs & (SSS-1)) == (SSS-1)) {
            const int b = bs >> 9;
            for (int j = 0; j < NN; ++j) {
                float a = 0.f;
                if (bits & (1u << j)) {
                    float e = esrc + x_s[bl][j] * t_h;
                    e = (e >= 0.f) ? e : 0.2f * e;
                    a = expf(e - m) / Z;
                }
                float ao = __shfl_xor(a, 32, 64);
                if (act && h == 0)
                    attn_out[b*(NN*NN) + i*NN + j] = 0.5f * (a + ao);
            }
        }
    }
    __syncthreads();

    const int p = t & 63, grp = t >> 6;
    float acc0 = 0.f, acc1 = 0.f, acc2 = 0.f, acc3 = 0.f;
    for (int c = 0; c < 5; ++c) {
        #pragma unroll
        for (int rep = 0; rep < 24; ++rep)
            wchunk[rep*256 + t] = W_proj[c*6144 + rep*256 + t];
        __syncthreads();
        for (int kk = 0; kk < 96; kk += 4) {
            float4 g0 = *(const float4*)&gat[grp*4 + 0][c*96 + kk];
            float4 g1 = *(const float4*)&gat[grp*4 + 1][c*96 + kk];
            float4 g2 = *(const float4*)&gat[grp*4 + 2][c*96 + kk];
            float4 g3 = *(const float4*)&gat[grp*4 + 3][c*96 + kk];
            float w0 = wchunk[(kk+0)*64 + p];
            float w1 = wchunk[(kk+1)*64 + p];
            float w2 = wchunk[(kk+2)*64 + p];
            float w3 = wchunk[(kk+3)*64 + p];
            acc0 += g0.x*w0 + g0.y*w1 + g0.z*w2 + g0.w*w3;
            acc1 += g1.x*w0 + g1.y*w1 + g1.z*w2 + g1.w*w3;
            acc2 += g2.x*w0 + g2.y*w1 + g2.z*w2 + g2.w*w3;
            acc3 += g3.x*w0 + g3.y*w1 + g3.z*w2 + g3.w*w3;
        }
        __syncthreads();
    }
    const float bp = b_proj[p];
    gat_seq[(bs_base + grp*4 + 0)*64 + p] = fmaxf(acc0 + bp, 0.f);
    gat_seq[(bs_base + grp*4 + 1)*64 + p] = fmaxf(acc1 + bp, 0.f);
    gat_seq[(bs_base + grp*4 + 2)*64 + p] = fmaxf(acc2 + bp, 0.f);
    gat_seq[(bs_base + grp*4 + 3)*64 + p] = fmaxf(acc3 + bp, 0.f);
}

// ------- K2a: input projection (no recurrence -> fully parallel GEMM) -------
__global__ __launch_bounds__(256) void xproj_kernel(
    const float* __restrict__ xin,   // (BS, 64)
    const float* __restrict__ W,     // (256, 64) row-major
    const float* __restrict__ b_ih, const float* __restrict__ b_hh,
    float* __restrict__ gx)          // (BS, 256)
{
    __shared__ __align__(16) float xt[64][64];   // 16 KB
    const int t = threadIdx.x;
    const int r0 = blockIdx.x * 64;

    for (int i = t; i < 64*16; i += 256) {       // float4 units
        int r = i >> 4, c4 = (i & 15) << 2;
        *(float4*)&xt[r][c4] = *(const float4*)&xin[(size_t)(r0 + r)*64 + c4];
    }
    float4 w[16];
    #pragma unroll
    for (int i = 0; i < 16; ++i) w[i] = *(const float4*)&W[t*64 + 4*i];
    const float bias = b_ih[t] + b_hh[t];
    __syncthreads();

    for (int r = 0; r < 64; ++r) {
        float a0 = 0.f, a1 = 0.f, a2 = 0.f, a3 = 0.f;
        #pragma unroll
        for (int i = 0; i < 16; ++i) {
            float4 v = *(const float4*)&xt[r][4*i];   // wave-uniform -> broadcast
            a0 = fmaf(v.x, w[i].x, a0); a1 = fmaf(v.y, w[i].y, a1);
            a2 = fmaf(v.z, w[i].z, a2); a3 = fmaf(v.w, w[i].w, a3);
        }
        gx[(size_t)(r0 + r)*256 + t] = bias + ((a0 + a1) + (a2 + a3));
    }
}

// ------- K2b: LSTM recurrence, in-wave gate gather, 1 barrier/step ---------
// 512 threads. lane l = (jj<<3)|(q<<1)|s : wave w owns cells j=8w+jj,
// q = gate (i,f,g,o), s = K-half (32 elems). 32 weight floats/thread (~60
// VGPR demand, under the allocator's ~88 cap -> structural residency, R9).
// Gates never touch LDS: slice-reduce via shfl_xor(1), gate gather via 4
// in-wave shfl, cell update replicated in all 8 lanes of the j-group.
// h ping-pong in LDS -> single barrier per step (R9: serial wave-0 cell
// phase + 2 barriers = ~700 of 1190 cyc/step).
__global__ __launch_bounds__(512) void lstm_rec_kernel(
    const float* __restrict__ gx,    // (B, S, 256) precomputed x-part + biases
    const float* __restrict__ W_hh,  // (256, 64)
    float* __restrict__ h_out)       // (B, S, 64)
{
    __shared__ __align__(16) float h_s[2][64];

    const int t = threadIdx.x;
    const int b = blockIdx.x;
    const int lane = t & 63;
    const int jj = lane >> 3, q = (lane >> 1) & 3, s = lane & 1;
    const int j = (t >> 6) * 8 + jj;     // cell index [0,64)
    const int row = q * 64 + j;          // gate row [0,256)
    const bool qg = (q == 2);            // tanh gate
    const int gbase = (jj << 3);         // lane base of this cell's group

    // 32 weight floats (8 float4) for K-half s
    float4 w0 = *(const float4*)&W_hh[row*64 + s*32 +  0];
    float4 w1 = *(const float4*)&W_hh[row*64 + s*32 +  4];
    float4 w2 = *(const float4*)&W_hh[row*64 + s*32 +  8];
    float4 w3 = *(const float4*)&W_hh[row*64 + s*32 + 12];
    float4 w4 = *(const float4*)&W_hh[row*64 + s*32 + 16];
    float4 w5 = *(const float4*)&W_hh[row*64 + s*32 + 20];
    float4 w6 = *(const float4*)&W_hh[row*64 + s*32 + 24];
    float4 w7 = *(const float4*)&W_hh[row*64 + s*32 + 28];
#define PIN4(v) asm volatile("" : "+v"(v.x), "+v"(v.y), "+v"(v.z), "+v"(v.w));
    PIN4(w0) PIN4(w1) PIN4(w2) PIN4(w3) PIN4(w4) PIN4(w5) PIN4(w6) PIN4(w7)
#undef PIN4

    if (t < 64) { h_s[0][t] = 0.f; }

    const float* __restrict__ gxb = gx + (size_t)b * SSS * 256;
    float* __restrict__ hrow = h_out + (size_t)b * SSS * 64;

    float c = 0.f;
    float gx_cur = gxb[row];
    __syncthreads();

    for (int tt = 0; tt < SSS; ++tt) {
        const int cur = tt & 1;
        float gx_next = (tt + 1 < SSS) ? gxb[(size_t)(tt+1)*256 + row] : 0.f;

        const float* hb = &h_s[cur][s*32];
        const float4 h0 = *(const float4*)&hb[0];
        const float4 h1 = *(const float4*)&hb[4];
        const float4 h2 = *(const float4*)&hb[8];
        const float4 h3 = *(const float4*)&hb[12];
        const float4 h4 = *(const float4*)&hb[16];
        const float4 h5 = *(const float4*)&hb[20];
        const float4 h6 = *(const float4*)&hb[24];
        const float4 h7 = *(const float4*)&hb[28];

        float a0 = h0.x*w0.x + h0.y*w0.y + h0.z*w0.z + h0.w*w0.w;
        float a1 = h1.x*w1.x + h1.y*w1.y + h1.z*w1.z + h1.w*w1.w;
        float a2 = h2.x*w2.x + h2.y*w2.y + h2.z*w2.z + h2.w*w2.w;
        float a3 = h3.x*w3.x + h3.y*w3.y + h3.z*w3.z + h3.w*w3.w;
        a0 = fmaf(h4.x, w4.x, a0); a0 = fmaf(h4.y, w4.y, a0);
        a0 = fmaf(h4.z, w4.z, a0); a0 = fmaf(h4.w, w4.w, a0);
        a1 = fmaf(h5.x, w5.x, a1); a1 = fmaf(h5.y, w5.y, a1);
        a1 = fmaf(h5.z, w5.z, a1); a1 = fmaf(h5.w, w5.w, a1);
        a2 = fmaf(h6.x, w6.x, a2); a2 = fmaf(h6.y, w6.y, a2);
        a2 = fmaf(h6.z, w6.z, a2); a2 = fmaf(h6.w, w6.w, a2);
        a3 = fmaf(h7.x, w7.x, a3); a3 = fmaf(h7.y, w7.y, a3);
        a3 = fmaf(h7.z, w7.z, a3); a3 = fmaf(h7.w, w7.w, a3);
        float acc = (a0 + a1) + (a2 + a3);

        acc += __shfl_xor(acc, 1, 64);        // combine the two K-halves
        acc += gx_cur;

        // divergence-free activation: tanh(x) = 2*sigmoid(2x) - 1
        float y = fsigmoid(qg ? 2.f * acc : acc);
        float act = qg ? fmaf(2.f, y, -1.f) : y;

        // gather i,f,g,o from lanes gbase+0/2/4/6 (in-wave)
        float ig = __shfl(act, gbase + 0, 64);
        float fg = __shfl(act, gbase + 2, 64);
        float gg = __shfl(act, gbase + 4, 64);
        float og = __shfl(act, gbase + 6, 64);

        c = fg * c + ig * gg;                 // replicated in all 8 lanes
        float hv = og * ftanh(c);

        if ((lane & 7) == 0) {
            h_s[cur ^ 1][j] = hv;
            hrow[(size_t)tt*64 + j] = hv;
        }
        gx_cur = gx_next;
        __syncthreads();
    }
}

// ---------------- K3: recon = h2 @ W_out + b_out ----------------
__global__ __launch_bounds__(256) void recon_kernel(
    const float* __restrict__ h2, const float* __restrict__ W_out,
    const float* __restrict__ b_out, float* __restrict__ out)
{
    __shared__ __align__(16) float hl[8*64];
    const int t = threadIdx.x;
    const int bs_base = blockIdx.x * 8;

    hl[t]       = h2[(size_t)bs_base*64 + t];
    hl[256 + t] = h2[(size_t)bs_base*64 + 256 + t];
    __syncthreads();

    if (t < 240) {
        const int bl = t / 30;
        const int n  = t - bl*30;
        float acc = b_out[n];
        #pragma unroll
        for (int k = 0; k < 64; ++k)
            acc += hl[bl*64 + k] * W_out[k*NN + n];
        out[(size_t)(bs_base + bl)*NN + n] = acc;
    }
}

extern "C" void kernel_launch(void* const* d_in, const int* in_sizes, int n_in,
                              void* d_out, int out_size, void* d_ws, size_t ws_size,
                              hipStream_t stream)
{
    const float* x      = (const float*)d_in[0];
    const float* adj    = (const float*)d_in[1];
    const float* W_gat  = (const float*)d_in[2];
    const float* a_src  = (const float*)d_in[3];
    const float* a_dst  = (const float*)d_in[4];
    const float* W_proj = (const float*)d_in[5];
    const float* b_proj = (const float*)d_in[6];
    const float* W_ih0  = (const float*)d_in[7];
    const float* W_hh0  = (const float*)d_in[8];
    const float* b_ih0  = (const float*)d_in[9];
    const float* b_hh0  = (const float*)d_in[10];
    const float* W_ih1  = (const float*)d_in[11];
    const float* W_hh1  = (const float*)d_in[12];
    const float* b_ih1  = (const float*)d_in[13];
    const float* b_hh1  = (const float*)d_in[14];
    const float* W_out  = (const float*)d_in[15];
    const float* b_out  = (const float*)d_in[16];

    float* out = (float*)d_out;
    float* gat_seq = (float*)d_ws;                       //  8.4 MB
    float* h1  = gat_seq + (size_t)BS_TOT*64;            //  8.4 MB
    float* h2  = h1 + (size_t)BS_TOT*64;                 //  8.4 MB
    float* gxb = h2 + (size_t)BS_TOT*64;                 // 33.5 MB

    hipLaunchKernelGGL(gat_proj_kernel, dim3(BS_TOT/NB), dim3(256), 0, stream,
                       x, adj, W_gat, a_src, a_dst, W_proj, b_proj,
                       gat_seq, out + RECON_SIZE);
    hipLaunchKernelGGL(xproj_kernel, dim3(BS_TOT/64), dim3(256), 0, stream,
                       gat_seq, W_ih0, b_ih0, b_hh0, gxb);
    hipLaunchKernelGGL(lstm_rec_kernel, dim3(BBB), dim3(512), 0, stream,
                       gxb, W_hh0, h1);
    hipLaunchKernelGGL(xproj_kernel, dim3(BS_TOT/64), dim3(256), 0, stream,
                       h1, W_ih1, b_ih1, b_hh1, gxb);
    hipLaunchKernelGGL(lstm_rec_kernel, dim3(BBB), dim3(512), 0, stream,
                       gxb, W_hh1, h2);
    hipLaunchKernelGGL(recon_kernel, dim3(BS_TOT/8), dim3(256), 0, stream,
                       h2, W_out, b_out, out);
}